// Round 4
// baseline (171.253 us; speedup 1.0000x reference)
//
#include <hip/hip_runtime.h>
#include <hip/hip_bf16.h>
#include <stdint.h>

#define NROWS 8192
#define DDIM  768       // elements per row
#define BM 256          // block rows
#define BN 128          // block cols
#define BKB 128         // K-bytes (=elements) per k-iteration
#define NKT  (DDIM / BKB)   // 6 K-iterations
#define QSCALE 508.0f   // int8 quant scale: 127/0.25
#define NTGT (2 * NROWS)
#define NPR 128         // partial slots per ROW target   (bx*2+wn)
#define NPC 64          // partial slots per COL target   (by*2+wm)

typedef int v4i  __attribute__((ext_vector_type(4)));
typedef int v16i __attribute__((ext_vector_type(16)));

__device__ __forceinline__ int imax(int a, int b) { return a > b ? a : b; }

__device__ __forceinline__ v16i vmax16(v16i a, v16i b) {
    v16i r;
    #pragma unroll
    for (int i = 0; i < 16; ++i) r[i] = imax(a[i], b[i]);
    return r;
}

__device__ __forceinline__ int pack4(float4 v, float k) {
    int x0 = __float2int_rn(v.x * k); x0 = imax(-127, x0); x0 = x0 > 127 ? 127 : x0;
    int x1 = __float2int_rn(v.y * k); x1 = imax(-127, x1); x1 = x1 > 127 ? 127 : x1;
    int x2 = __float2int_rn(v.z * k); x2 = imax(-127, x2); x2 = x2 > 127 ? 127 : x2;
    int x3 = __float2int_rn(v.w * k); x3 = imax(-127, x3); x3 = x3 > 127 ? 127 : x3;
    return (x0 & 0xff) | ((x1 & 0xff) << 8) | ((x2 & 0xff) << 16) | ((x3 & 0xff) << 24);
}

// ---- 1: row-normalize + int8 quantize. Wave per row. ----
// BOTH X and Y stored FRAGMENT-MAJOR (verified round 2): int8 of row
// (rb*32+fr), k-bytes [c*16,+16) live at buf[((rb*48+c)*32+fr)*16], c in
// [0,48). A wave's fragment load is then one global_load_dwordx4: lane
// (fr,h) reads v4i index ((rb*48 + c)*32 + fr) where c = kt*8 + ks*2 + h.
__global__ __launch_bounds__(256) void norm_quant_kernel(
        const float* __restrict__ ex, const float* __restrict__ ey,
        char* __restrict__ Xqf, char* __restrict__ Yqf) {
    int row  = blockIdx.x * 4 + (threadIdx.x >> 6);
    int lane = threadIdx.x & 63;
    const float* src;
    char* dst;
    int r;
    if (row < NROWS) { src = ex + (size_t)row * DDIM; dst = Xqf; r = row; }
    else             { src = ey + (size_t)(row - NROWS) * DDIM; dst = Yqf; r = row - NROWS; }
    const float4* s4 = (const float4*)src;
    float4 a = s4[lane], b = s4[lane + 64], c = s4[lane + 128];
    float ss = a.x*a.x + a.y*a.y + a.z*a.z + a.w*a.w
             + b.x*b.x + b.y*b.y + b.z*b.z + b.w*b.w
             + c.x*c.x + c.y*c.y + c.z*c.z + c.w*c.w;
    #pragma unroll
    for (int off = 32; off > 0; off >>= 1) ss += __shfl_xor(ss, off, 64);
    float k = rsqrtf(ss) * QSCALE;   // norms ~27.7; reference's 1e-8 clamp never binds
    int rb = r >> 5, fr = r & 31;
    int cbase = lane >> 2, wofs = lane & 3;    // lane's dword j covers chunk cbase+j*16
    int* dq = (int*)dst;
    dq[((rb * 48 + cbase     ) * 32 + fr) * 4 + wofs] = pack4(a, k);
    dq[((rb * 48 + cbase + 16) * 32 + fr) * 4 + wofs] = pack4(b, k);
    dq[((rb * 48 + cbase + 32) * 32 + fr) * 4 + wofs] = pack4(c, k);
}

// ---- 2: int8 NT-GEMM, BARRIER-FREE all-register main loop ----
// Round-4 restructure. Rounds 1/3 showed schedule edits on the LDS-staged
// 2-barrier structure are neutral-to-negative: the barrier lockstep couples
// the MFMA / LDS / L2 pipes (each ~23-32 us/CU) into a 62 us serial-ish
// critical path. Fix: remove the coupling. Both operands are fragment-major
// in global; each wave loads its A/B fragments straight to registers from
// L2 (no LDS, no barriers, no waitcnt pins in the main loop). Block =
// 2x2 waves over a 256x128 tile -> each operand duplicated only 2x; L2
// traffic 1.18 GB = same floor as the LDS version, but waves are fully
// independent so load latency hides under MFMAs across kt boundaries.
// Wave tile 128x64 = acc[4][2] (128 VGPRs).
// Reg audit (round-2 lesson: cap = 512/min_waves_per_EU): (256,2) -> 256
// cap; demand = 128 acc + 96 in-flight frags + addr ~ 235. Spill signature
// to watch in counters: WRITE_SIZE >> 11 MB.
__global__ __launch_bounds__(256, 2) void gemm_max_kernel(
        const char* __restrict__ Xqf, const char* __restrict__ Yqf,
        int* __restrict__ P) {   // rows: P[t*128]; cols: P + 4MB, [c*64]
    __shared__ __align__(16) int Ts[4 * 1152];   // epilogue transpose scratch only

    const int tid  = threadIdx.x;
    const int lane = tid & 63;
    const int wave = tid >> 6;     // 0..3
    const int wm   = wave >> 1;    // 0..1 : 128-row half
    const int wn   = wave & 1;     // 0..1 : 64-col half

    // XCD-aware decode: 2048 blocks = 8 xcd * 256 (16bx x 16by patch per XCD)
    const int b  = blockIdx.x;
    const int p  = b & 7;
    const int w  = b >> 3;                    // 0..255
    const int bx = (p & 3) * 16 + (w & 15);   // 0..63  (128-col blocks)
    const int by = (p >> 2) * 16 + (w >> 4);  // 0..31  (256-row blocks)

    const int row0 = by * BM;   // X rows
    const int col0 = bx * BN;   // Y rows (C columns)

    // fragment addressing: row-in-block fr = lane&31, 16B-half h = lane>>5
    const int fr = lane & 31;
    const int h  = lane >> 5;

    // A: row-block rb = row0/32 + wm*4 + mt; frag (mt,kt,ks) at
    //    gA + (mt*48 + kt*8 + ks*2)*32 v4i. B mirrors with cb.
    const int rb0 = (row0 >> 5) + wm * 4;
    const v4i* gA = (const v4i*)Xqf + ((size_t)(rb0 * 48 + h) * 32 + fr);
    const int cb0 = (col0 >> 5) + wn * 2;
    const v4i* gB = (const v4i*)Yqf + ((size_t)(cb0 * 48 + h) * 32 + fr);

    v16i acc[4][2] = {};

    for (int kt = 0; kt < NKT; ++kt) {
        #pragma unroll
        for (int ks = 0; ks < 4; ++ks) {
            v4i af[4], bf[2];
            #pragma unroll
            for (int mt = 0; mt < 4; ++mt)
                af[mt] = gA[(mt * 48 + kt * 8 + ks * 2) * 32];
            #pragma unroll
            for (int nt = 0; nt < 2; ++nt)
                bf[nt] = gB[(nt * 48 + kt * 8 + ks * 2) * 32];
            #pragma unroll
            for (int mt = 0; mt < 4; ++mt)
                #pragma unroll
                for (int nt = 0; nt < 2; ++nt)
                    acc[mt][nt] = __builtin_amdgcn_mfma_i32_32x32x32_i8(
                        af[mt], bf[nt], acc[mt][nt], 0, 0, 0);
        }
    }

    // C/D (32x32): col = lane&31 (=fr), row = (reg&3) + 8*(reg>>2) + 4*h
    int* Pc = P + (size_t)NROWS * NPR;   // col-partial region

    // ---- col partials (cheap direction: regs + one shuffle) ----
    #pragma unroll
    for (int nt = 0; nt < 2; ++nt) {
        v16i c = vmax16(vmax16(acc[0][nt], acc[1][nt]),
                        vmax16(acc[2][nt], acc[3][nt]));
        int v = c[0];
        #pragma unroll
        for (int i = 1; i < 16; ++i) v = imax(v, c[i]);
        v = imax(v, __shfl_xor(v, 32, 64));        // combine the two k-halves' rows
        if (h == 0) {
            int col = col0 + wn * 64 + nt * 32 + fr;
            Pc[(size_t)col * NPC + by * 2 + wm] = v;   // sole writer
        }
    }

    // ---- row partials via LDS transpose (wave-private scratch; lgkm only) ----
    int* T = Ts + wave * 1152;   // 32 x 36 ints per wave (4608 B)
    const int rrow = lane & 31, seg = lane >> 5;
    #pragma unroll
    for (int mt = 0; mt < 4; ++mt) {
        v16i m = vmax16(acc[mt][0], acc[mt][1]);
        #pragma unroll
        for (int reg = 0; reg < 16; ++reg) {
            int rl = (reg & 3) + 8 * (reg >> 2) + 4 * h;   // local row 0..31
            T[rl * 36 + fr] = m[reg];
        }
        __builtin_amdgcn_s_waitcnt(0);                     // lgkm drain before transpose read
        const v4i* tr = (const v4i*)(T + rrow * 36 + seg * 16);
        v4i a0 = tr[0], a1 = tr[1], a2 = tr[2], a3 = tr[3];
        v4i m01 = { imax(a0[0],a1[0]), imax(a0[1],a1[1]), imax(a0[2],a1[2]), imax(a0[3],a1[3]) };
        v4i m23 = { imax(a2[0],a3[0]), imax(a2[1],a3[1]), imax(a2[2],a3[2]), imax(a2[3],a3[3]) };
        int v = imax(imax(m01[0], m23[0]), imax(m01[1], m23[1]));
        v = imax(v, imax(imax(m01[2], m23[2]), imax(m01[3], m23[3])));
        v = imax(v, __shfl_xor(v, 32, 64));                // combine the two 16-int segments
        if (seg == 0) {
            int row = row0 + wm * 128 + mt * 32 + rrow;
            P[(size_t)row * NPR + bx * 2 + wn] = v;        // sole writer
        }
        __builtin_amdgcn_s_waitcnt(0);                     // reads done before next mt overwrites T
    }
}

// ---- 3: reduce partials -> one max per target (wave per target) ----
// rows (t<8192): 128 partials; cols: 64 partials.
__global__ __launch_bounds__(256) void reduce_kernel(
        const int* __restrict__ P, int* __restrict__ maxes) {
    int t    = blockIdx.x * 4 + (threadIdx.x >> 6);
    int lane = threadIdx.x & 63;
    int v;
    if (t < NROWS) {
        const int* p = P + (size_t)t * NPR;
        v = imax(p[lane], p[lane + 64]);
    } else {
        const int* p = P + (size_t)NROWS * NPR + (size_t)(t - NROWS) * NPC;
        v = p[lane];
    }
    #pragma unroll
    for (int off = 1; off < 64; off <<= 1)
        v = imax(v, __shfl_xor(v, off, 64));
    if (lane == 0) maxes[t] = v;
}

// ---- 4: entropy of Normal log-probs of (1 + max) ----
__global__ __launch_bounds__(256) void finalize_kernel(
        const int* __restrict__ maxes, float* __restrict__ out) {
    int which = blockIdx.x;
    const int* m = maxes + which * NROWS;
    int t = threadIdx.x;
    float s = 0.0f;
    const float dq = 1.0f / (QSCALE * QSCALE);
    for (int i = t; i < NROWS; i += 256) {
        float f = (float)m[i] * dq;
        float z = f * (1.0f / 0.3f);
        float c = -0.5f * z * z + 0.28503427f;
        s += expf(c) * c;
    }
    #pragma unroll
    for (int off = 32; off > 0; off >>= 1) s += __shfl_down(s, off, 64);
    __shared__ float red[4];
    if ((t & 63) == 0) red[t >> 6] = s;
    __syncthreads();
    if (t == 0) out[which] = -(red[0] + red[1] + red[2] + red[3]);
}

extern "C" void kernel_launch(void* const* d_in, const int* in_sizes, int n_in,
                              void* d_out, int out_size, void* d_ws, size_t ws_size,
                              hipStream_t stream) {
    const float* ex = (const float*)d_in[0];
    const float* ey = (const float*)d_in[1];
    float* out = (float*)d_out;

    char* ws = (char*)d_ws;
    char* Xqf   = ws;                                            // 6.29 MB fragment-major
    char* Yqf   = ws + (size_t)NROWS * DDIM;                     // 6.29 MB fragment-major
    int*  P     = (int*)(ws + (size_t)2 * NROWS * DDIM);         // 4 MB rows + 2 MB cols
    int*  maxes = P + (size_t)NROWS * NPR + (size_t)NROWS * NPC; // 64 KB

    hipLaunchKernelGGL(norm_quant_kernel, dim3(2 * NROWS / 4), dim3(256), 0, stream,
                       ex, ey, Xqf, Yqf);
    hipLaunchKernelGGL(gemm_max_kernel, dim3((NROWS / BM) * (NROWS / BN)), dim3(256), 0, stream,
                       Xqf, Yqf, P);
    hipLaunchKernelGGL(reduce_kernel, dim3(NTGT / 4), dim3(256), 0, stream, P, maxes);
    hipLaunchKernelGGL(finalize_kernel, dim3(2), dim3(256), 0, stream, maxes, out);
}

// Round 5
// 148.605 us; speedup vs baseline: 1.1524x; 1.1524x over previous
//
#include <hip/hip_runtime.h>
#include <hip/hip_bf16.h>
#include <stdint.h>

#define NROWS 8192
#define DDIM  768       // elements per row
#define BM 128          // block rows (X)
#define BN 256          // block cols (Y) -- 4 waves x 64 cols, B never duplicated
#define BKB 128         // K-bytes (=elements) per staged tile
#define NKT  (DDIM / BKB)   // 6 K-iterations
#define QSCALE 508.0f   // int8 quant scale: 127/0.25
#define NTGT (2 * NROWS)
#define NPR 128         // partial slots per ROW target   (bx*4+wave), bx<32
#define NPC 64          // partial slots per COL target   (by), by<64

typedef int v4i  __attribute__((ext_vector_type(4)));
typedef int v16i __attribute__((ext_vector_type(16)));

__device__ __forceinline__ int imax(int a, int b) { return a > b ? a : b; }

__device__ __forceinline__ v16i vmax16(v16i a, v16i b) {
    v16i r;
    #pragma unroll
    for (int i = 0; i < 16; ++i) r[i] = imax(a[i], b[i]);
    return r;
}

// async global->LDS, 16B per lane; LDS dest = wave-uniform base + lane*16
__device__ __forceinline__ void async_ld16(const void* g, uintptr_t lds_addr) {
    __builtin_amdgcn_global_load_lds(
        (const __attribute__((address_space(1))) void*)(uintptr_t)g,
        (__attribute__((address_space(3))) void*)(uint32_t)lds_addr,
        16, 0, 0);
}

__device__ __forceinline__ int pack4(float4 v, float k) {
    int x0 = __float2int_rn(v.x * k); x0 = imax(-127, x0); x0 = x0 > 127 ? 127 : x0;
    int x1 = __float2int_rn(v.y * k); x1 = imax(-127, x1); x1 = x1 > 127 ? 127 : x1;
    int x2 = __float2int_rn(v.z * k); x2 = imax(-127, x2); x2 = x2 > 127 ? 127 : x2;
    int x3 = __float2int_rn(v.w * k); x3 = imax(-127, x3); x3 = x3 > 127 ? 127 : x3;
    return (x0 & 0xff) | ((x1 & 0xff) << 8) | ((x2 & 0xff) << 16) | ((x3 & 0xff) << 24);
}

// ---- 1: row-normalize + int8 quantize. Wave per row. (verified, round 0) ----
// X rows -> row-major Xq (for LDS staging). Y rows -> FRAGMENT-MAJOR Yqf:
// int8 of Y row (cb*32+fr), k-bytes [c*16,+16) live at Yqf[((cb*48+c)*32+fr)*16].
__global__ __launch_bounds__(256) void norm_quant_kernel(
        const float* __restrict__ ex, const float* __restrict__ ey,
        char* __restrict__ Xq, char* __restrict__ Yqf) {
    int row  = blockIdx.x * 4 + (threadIdx.x >> 6);
    int lane = threadIdx.x & 63;
    const float* src = (row < NROWS) ? ex + (size_t)row * DDIM
                                     : ey + (size_t)(row - NROWS) * DDIM;
    const float4* s4 = (const float4*)src;
    float4 a = s4[lane], b = s4[lane + 64], c = s4[lane + 128];
    float ss = a.x*a.x + a.y*a.y + a.z*a.z + a.w*a.w
             + b.x*b.x + b.y*b.y + b.z*b.z + b.w*b.w
             + c.x*c.x + c.y*c.y + c.z*c.z + c.w*c.w;
    #pragma unroll
    for (int off = 32; off > 0; off >>= 1) ss += __shfl_xor(ss, off, 64);
    float k = rsqrtf(ss) * QSCALE;   // norms ~27.7; reference's 1e-8 clamp never binds
    if (row < NROWS) {
        int* d4 = (int*)(Xq + (size_t)row * DDIM);
        d4[lane]       = pack4(a, k);
        d4[lane + 64]  = pack4(b, k);
        d4[lane + 128] = pack4(c, k);
    } else {
        int r  = row - NROWS;
        int cb = r >> 5, fr = r & 31;
        int cbase = lane >> 2, wofs = lane & 3;    // lane's dword j covers chunk cbase+j*16
        int* dq = (int*)Yqf;
        dq[((cb * 48 + cbase     ) * 32 + fr) * 4 + wofs] = pack4(a, k);
        dq[((cb * 48 + cbase + 16) * 32 + fr) * 4 + wofs] = pack4(b, k);
        dq[((cb * 48 + cbase + 32) * 32 + fr) * 4 + wofs] = pack4(c, k);
    }
}

// ---- 2: int8 NT-GEMM, 128x256 tile, 4 waves 1x4, ZERO B-duplication ----
// Round-5 analysis: every prior variant kept L2->CU traffic at 4.6 MB/CU
// (82 K cyc -- the heaviest pipe); schedule edits were neutral because time
// >= max(pipes) and the max pipe never shrank. This geometry halves VMEM:
// each wave owns a 128x64 col slice, so B cols are loaded by exactly one
// wave (no dup) and A is staged once in LDS. 2.3 MB/CU = 41 K cyc < MFMA
// 56 K cyc -> matrix pipe is now the top pipe. Schedule/staging/swizzle are
// byte-identical to the verified round-0 kernel (2-barrier; schedule edits
// proved neutral in rounds 1/3, so none attempted).
// Reg audit (round-2 lesson: cap = 512/min_waves_per_EU): (256,2) -> 256;
// demand = 128 acc(AGPR) + 32 bf + 16 af + ~25 addr ~= 200. 2 blocks/CU.
__global__ __launch_bounds__(256, 2) void gemm_max_kernel(
        const char* __restrict__ Xq, const char* __restrict__ Yqf,
        int* __restrict__ P) {   // rows: P[t*128], t<8192; cols: P + 4MB, [c*64]
    __shared__ __align__(16) char S[18432];   // A staging 16 KB; epilogue 18 KB

    const int tid  = threadIdx.x;
    const int lane = tid & 63;
    const int wave = tid >> 6;     // 0..3 : 64-col slice owner

    // XCD-aware decode: 2048 blocks = 8 xcd * 256 (16bx x 16by patch per XCD)
    const int b  = blockIdx.x;
    const int p  = b & 7;
    const int w  = b >> 3;                    // 0..255
    const int bx = (p & 1) * 16 + (w & 15);   // 0..31  (256-col blocks)
    const int by = (p >> 1) * 16 + (w >> 4);  // 0..63  (128-row blocks)

    const int row0 = by * BM;   // X rows
    const int col0 = bx * BN;   // Y rows (C columns)

    // A staging (identical to round 0): wave stages rows [wave*32,+32) as 4
    // chunks of 8 rows; LDS row r at (r*128), 16B slot c at ((c^(r&7))*16).
    const int srow = lane >> 3;
    const int sswz = (lane & 7) ^ srow;            // swizzled 16B slot
    const char* gA = Xq + (size_t)(row0 + wave * 32 + srow) * DDIM + sswz * 16;
    const uintptr_t ldsA = (uintptr_t)(void*)S + (unsigned)(wave * 4096);

    // fragment addressing: row fr = lane&31, k-half h = lane>>5
    const int fr = lane & 31;
    const int h  = lane >> 5;
    const int fswz = fr & 7;

    // B: fragment-major global. Wave's cols = col0 + wave*64. Fragment
    // (nt,kt,ks) at gB + (nt*48 + kt*8 + ks*2)*32 v4i (nt advances one cb).
    const int cb0 = (col0 >> 5) + wave * 2;
    const v4i* gB = (const v4i*)Yqf + ((size_t)(cb0 * 48 + h) * 32 + fr);

    v16i acc[4][2] = {};   // [mt: 4x32 rows][nt: 2x32 cols]

    for (int kt = 0; kt < NKT; ++kt) {
        // B fragments for this kt -- issued first (longest latency)
        v4i bf[4][2];
        #pragma unroll
        for (int ks = 0; ks < 4; ++ks)
            #pragma unroll
            for (int nt = 0; nt < 2; ++nt)
                bf[ks][nt] = gB[(nt * 48 + kt * 8 + ks * 2) * 32];
        // A staging: 16 KB total, this wave's 4 chunks
        const char* ga = gA + kt * BKB;
        #pragma unroll
        for (int j = 0; j < 4; ++j)
            async_ld16(ga + j * (8 * DDIM), ldsA + j * 1024);
        __syncthreads();   // drains A staging AND B loads together
        #pragma unroll
        for (int ks = 0; ks < 4; ++ks) {
            v4i af[4];
            const int swz = ((ks * 2 + h) ^ fswz) * 16;
            #pragma unroll
            for (int mt = 0; mt < 4; ++mt)
                af[mt] = *(const v4i*)(S + (mt * 32 + fr) * BKB + swz);
            #pragma unroll
            for (int mt = 0; mt < 4; ++mt)
                #pragma unroll
                for (int nt = 0; nt < 2; ++nt)
                    acc[mt][nt] = __builtin_amdgcn_mfma_i32_32x32x32_i8(
                        af[mt], bf[ks][nt], acc[mt][nt], 0, 0, 0);
        }
        __syncthreads();   // all waves done reading A before next stage
    }

    // C/D (32x32): col = lane&31 (=fr), row = (reg&3) + 8*(reg>>2) + 4*h
    int* Pc = P + (size_t)NROWS * NPR;   // col-partial region

    // ---- col partials (cheap direction: regs + one shuffle) ----
    // max over all 128 block rows of this wave's columns; sole writer per col.
    #pragma unroll
    for (int nt = 0; nt < 2; ++nt) {
        v16i c = vmax16(vmax16(acc[0][nt], acc[1][nt]),
                        vmax16(acc[2][nt], acc[3][nt]));
        int v = c[0];
        #pragma unroll
        for (int i = 1; i < 16; ++i) v = imax(v, c[i]);
        v = imax(v, __shfl_xor(v, 32, 64));        // combine the two k-halves' rows
        if (h == 0) {
            int col = col0 + wave * 64 + nt * 32 + fr;
            Pc[(size_t)col * NPC + by] = v;            // sole writer
        }
    }

    // ---- row partials via LDS transpose (wave-private scratch in S) ----
    int* T = (int*)(void*)S + wave * 1152;   // 32 x 36 ints per wave (4608 B)
    const int rrow = lane & 31, seg = lane >> 5;
    #pragma unroll
    for (int mt = 0; mt < 4; ++mt) {
        v16i m = vmax16(acc[mt][0], acc[mt][1]);   // max over this wave's 64 cols
        #pragma unroll
        for (int reg = 0; reg < 16; ++reg) {
            int rl = (reg & 3) + 8 * (reg >> 2) + 4 * h;   // local row 0..31
            T[rl * 36 + fr] = m[reg];
        }
        __builtin_amdgcn_s_waitcnt(0);                     // lgkm drain before transpose read
        const v4i* tr = (const v4i*)(T + rrow * 36 + seg * 16);
        v4i a0 = tr[0], a1 = tr[1], a2 = tr[2], a3 = tr[3];
        v4i m01 = { imax(a0[0],a1[0]), imax(a0[1],a1[1]), imax(a0[2],a1[2]), imax(a0[3],a1[3]) };
        v4i m23 = { imax(a2[0],a3[0]), imax(a2[1],a3[1]), imax(a2[2],a3[2]), imax(a2[3],a3[3]) };
        int v = imax(imax(m01[0], m23[0]), imax(m01[1], m23[1]));
        v = imax(v, imax(imax(m01[2], m23[2]), imax(m01[3], m23[3])));
        v = imax(v, __shfl_xor(v, 32, 64));                // combine the two 16-int segments
        if (seg == 0) {
            int row = row0 + mt * 32 + rrow;
            P[(size_t)row * NPR + bx * 4 + wave] = v;      // sole writer
        }
        __builtin_amdgcn_s_waitcnt(0);                     // reads done before next mt overwrites T
    }
}

// ---- 3: reduce partials -> one max per target (wave per target) ----
// rows (t<8192): 128 partials; cols: 64 partials.
__global__ __launch_bounds__(256) void reduce_kernel(
        const int* __restrict__ P, int* __restrict__ maxes) {
    int t    = blockIdx.x * 4 + (threadIdx.x >> 6);
    int lane = threadIdx.x & 63;
    int v;
    if (t < NROWS) {
        const int* p = P + (size_t)t * NPR;
        v = imax(p[lane], p[lane + 64]);
    } else {
        const int* p = P + (size_t)NROWS * NPR + (size_t)(t - NROWS) * NPC;
        v = p[lane];
    }
    #pragma unroll
    for (int off = 1; off < 64; off <<= 1)
        v = imax(v, __shfl_xor(v, off, 64));
    if (lane == 0) maxes[t] = v;
}

// ---- 4: entropy of Normal log-probs of (1 + max) ----
__global__ __launch_bounds__(256) void finalize_kernel(
        const int* __restrict__ maxes, float* __restrict__ out) {
    int which = blockIdx.x;
    const int* m = maxes + which * NROWS;
    int t = threadIdx.x;
    float s = 0.0f;
    const float dq = 1.0f / (QSCALE * QSCALE);
    for (int i = t; i < NROWS; i += 256) {
        float f = (float)m[i] * dq;
        float z = f * (1.0f / 0.3f);
        float c = -0.5f * z * z + 0.28503427f;
        s += expf(c) * c;
    }
    #pragma unroll
    for (int off = 32; off > 0; off >>= 1) s += __shfl_down(s, off, 64);
    __shared__ float red[4];
    if ((t & 63) == 0) red[t >> 6] = s;
    __syncthreads();
    if (t == 0) out[which] = -(red[0] + red[1] + red[2] + red[3]);
}

extern "C" void kernel_launch(void* const* d_in, const int* in_sizes, int n_in,
                              void* d_out, int out_size, void* d_ws, size_t ws_size,
                              hipStream_t stream) {
    const float* ex = (const float*)d_in[0];
    const float* ey = (const float*)d_in[1];
    float* out = (float*)d_out;

    char* ws = (char*)d_ws;
    char* Xq    = ws;                                            // 6.29 MB row-major
    char* Yqf   = ws + (size_t)NROWS * DDIM;                     // 6.29 MB fragment-major
    int*  P     = (int*)(ws + (size_t)2 * NROWS * DDIM);         // 4 MB rows + 2 MB cols
    int*  maxes = P + (size_t)NROWS * NPR + (size_t)NROWS * NPC; // 64 KB

    hipLaunchKernelGGL(norm_quant_kernel, dim3(2 * NROWS / 4), dim3(256), 0, stream,
                       ex, ey, Xq, Yqf);
    hipLaunchKernelGGL(gemm_max_kernel, dim3((NROWS / BM) * (NROWS / BN)), dim3(256), 0, stream,
                       Xq, Yqf, P);
    hipLaunchKernelGGL(reduce_kernel, dim3(NTGT / 4), dim3(256), 0, stream, P, maxes);
    hipLaunchKernelGGL(finalize_kernel, dim3(2), dim3(256), 0, stream, maxes, out);
}

// Round 6
// 146.556 us; speedup vs baseline: 1.1685x; 1.0140x over previous
//
#include <hip/hip_runtime.h>
#include <hip/hip_bf16.h>
#include <stdint.h>

#define NROWS 8192
#define DDIM  768       // elements per row
#define BM 128          // block rows (X)
#define BN 256          // block cols (Y) -- 4 waves x 64 cols, B never duplicated
#define BKB 128         // K-bytes (=elements) per k-iteration
#define NKT  (DDIM / BKB)   // 6 K-iterations
#define QSCALE 508.0f   // int8 quant scale: 127/0.25
#define NTGT (2 * NROWS)
#define NPR 128         // partial slots per ROW target   (bx*4+wave), bx<32
#define NPC 64          // partial slots per COL target   (by), by<64

typedef int v4i  __attribute__((ext_vector_type(4)));
typedef int v16i __attribute__((ext_vector_type(16)));

__device__ __forceinline__ int imax(int a, int b) { return a > b ? a : b; }

__device__ __forceinline__ v16i vmax16(v16i a, v16i b) {
    v16i r;
    #pragma unroll
    for (int i = 0; i < 16; ++i) r[i] = imax(a[i], b[i]);
    return r;
}

// async global->LDS, 16B per lane; LDS dest = wave-uniform base + lane*16
__device__ __forceinline__ void async_ld16(const void* g, uintptr_t lds_addr) {
    __builtin_amdgcn_global_load_lds(
        (const __attribute__((address_space(1))) void*)(uintptr_t)g,
        (__attribute__((address_space(3))) void*)(uint32_t)lds_addr,
        16, 0, 0);
}

__device__ __forceinline__ int pack4(float4 v, float k) {
    int x0 = __float2int_rn(v.x * k); x0 = imax(-127, x0); x0 = x0 > 127 ? 127 : x0;
    int x1 = __float2int_rn(v.y * k); x1 = imax(-127, x1); x1 = x1 > 127 ? 127 : x1;
    int x2 = __float2int_rn(v.z * k); x2 = imax(-127, x2); x2 = x2 > 127 ? 127 : x2;
    int x3 = __float2int_rn(v.w * k); x3 = imax(-127, x3); x3 = x3 > 127 ? 127 : x3;
    return (x0 & 0xff) | ((x1 & 0xff) << 8) | ((x2 & 0xff) << 16) | ((x3 & 0xff) << 24);
}

// ---- 1: row-normalize + int8 quantize. Wave per row. (verified round 2) ----
// BOTH X and Y stored FRAGMENT-MAJOR: int8 of row (rb*32+fr), k-bytes
// [c*16,+16) live at buf[((rb*48+c)*32+fr)*16], c in [0,48).
__global__ __launch_bounds__(256) void norm_quant_kernel(
        const float* __restrict__ ex, const float* __restrict__ ey,
        char* __restrict__ Xqf, char* __restrict__ Yqf) {
    int row  = blockIdx.x * 4 + (threadIdx.x >> 6);
    int lane = threadIdx.x & 63;
    const float* src;
    char* dst;
    int r;
    if (row < NROWS) { src = ex + (size_t)row * DDIM; dst = Xqf; r = row; }
    else             { src = ey + (size_t)(row - NROWS) * DDIM; dst = Yqf; r = row - NROWS; }
    const float4* s4 = (const float4*)src;
    float4 a = s4[lane], b = s4[lane + 64], c = s4[lane + 128];
    float ss = a.x*a.x + a.y*a.y + a.z*a.z + a.w*a.w
             + b.x*b.x + b.y*b.y + b.z*b.z + b.w*b.w
             + c.x*c.x + c.y*c.y + c.z*c.z + c.w*c.w;
    #pragma unroll
    for (int off = 32; off > 0; off >>= 1) ss += __shfl_xor(ss, off, 64);
    float k = rsqrtf(ss) * QSCALE;   // norms ~27.7; reference's 1e-8 clamp never binds
    int rb = r >> 5, fr = r & 31;
    int cbase = lane >> 2, wofs = lane & 3;    // lane's dword j covers chunk cbase+j*16
    int* dq = (int*)dst;
    dq[((rb * 48 + cbase     ) * 32 + fr) * 4 + wofs] = pack4(a, k);
    dq[((rb * 48 + cbase + 16) * 32 + fr) * 4 + wofs] = pack4(b, k);
    dq[((rb * 48 + cbase + 32) * 32 + fr) * 4 + wofs] = pack4(c, k);
}

// ---- 2: int8 NT-GEMM, 128x256 tile, 4 waves 1x4, latency-pipelined ----
// Round-6 analysis: gemm time was invariant at 62us across schedule AND
// traffic changes (R0/R3/R5) with MfmaUtil pinned ~35%. The invariant term
// is per-kt LATENCY EXPOSURE: B(kt) was always consumed in the same kt it
// was issued, so each wave absorbed ~full load latency per kt, with only
// 2-way cross-block overlap. Fix (distance-1 prefetch): B(kt+1) -> regs and
// A(kt+1) -> other LDS buffer are issued BEFORE compute(kt); the end-of-kt
// barrier drain then covers loads issued ~1400cyc earlier (near-free).
// Second fix: A is fragment-major in global (R2-verified), staged as
// contiguous 1KB DMAs, read back LANE-LINEAR -> zero bank conflicts
// (R2 measured SQ_LDS_BANK_CONFLICT=0 with this pattern; R0/R5's row-major
// A-read was a structural 4-way b128 alias, 3.15M conflict cycles).
// Geometry = R5 (zero B-dup, 2.3MB/CU VMEM).
// Reg audit (R2 lesson: cap = 512/min_waves_per_EU; (256,2) -> 256):
// acc 128 + bf 2x32 + af 4 + addr ~25 ~= 225. Spill signature: WRITE_SIZE.
__global__ __launch_bounds__(256, 2) void gemm_max_kernel(
        const char* __restrict__ Xqf, const char* __restrict__ Yqf,
        int* __restrict__ P) {   // rows: P[t*128], t<8192; cols: P + 4MB, [c*64]
    __shared__ __align__(16) char S[32768];   // 2 x 16KB A staging; epilogue reuse

    const int tid  = threadIdx.x;
    const int lane = tid & 63;
    const int wave = tid >> 6;     // 0..3 : 64-col slice owner; also stages row-block `wave`

    // XCD-aware decode: 2048 blocks = 8 xcd * 256 (16bx x 16by patch per XCD)
    const int b  = blockIdx.x;
    const int p  = b & 7;
    const int w  = b >> 3;                    // 0..255
    const int bx = (p & 1) * 16 + (w & 15);   // 0..31  (256-col blocks)
    const int by = (p >> 1) * 16 + (w >> 4);  // 0..63  (128-row blocks)

    const int row0 = by * BM;   // X rows
    const int col0 = bx * BN;   // Y rows (C columns)

    // fragment addressing: row fr = lane&31, k-half h = lane>>5
    const int fr = lane & 31;
    const int h  = lane >> 5;

    // A staging source: this wave's row-block rb, fragment-major; for kt the
    // 8 chunks [kt*8,+8) x 32 rows x 16B = 4KB are CONTIGUOUS at
    // rb*24576 + kt*4096. DMA'd as 4 x 1KB, lane-linear.
    const int rb = (row0 >> 5) + wave;
    const char* gA = Xqf + (size_t)rb * 24576 + lane * 16;
    const uintptr_t ldsA = (uintptr_t)(void*)S + (unsigned)(wave * 4096);

    // B: fragment-major global. Wave's cols = col0 + wave*64. Fragment
    // (nt,kt,ks) at gB + (nt*48 + kt*8 + ks*2)*32 v4i.
    const int cb0 = (col0 >> 5) + wave * 2;
    const v4i* gB = (const v4i*)Yqf + ((size_t)(cb0 * 48 + h) * 32 + fr);

    // A ds_read: LANE-LINEAR. Fragment (mt,ks,h) at S + buf*16384 +
    // mt*4096 + (ks*2+h)*512 + fr*16 = (S + lane*16) + buf*16384 +
    // mt*4096 + ks*1024  -> one addr VGPR + immediate offsets, 0 conflicts.
    const char* Sr = S + lane * 16;

    v16i acc[4][2] = {};   // [mt: 4x32 rows][nt: 2x32 cols]
    v4i bf[2][4][2];       // [buf][ks][nt] -- kt unrolled => static indexing

    // prologue: stage A(0) into buf0, load B(0); one exposed-latency drain
    #pragma unroll
    for (int j = 0; j < 4; ++j)
        async_ld16(gA + j * 1024, ldsA + j * 1024);
    #pragma unroll
    for (int ks = 0; ks < 4; ++ks)
        #pragma unroll
        for (int nt = 0; nt < 2; ++nt)
            bf[0][ks][nt] = gB[(nt * 48 + ks * 2) * 32];
    __syncthreads();

    #pragma unroll
    for (int kt = 0; kt < NKT; ++kt) {
        const int cur = kt & 1;
        // ---- distance-1 prefetch: B(kt+1) -> regs, A(kt+1) -> other buffer.
        // Issued BEFORE compute so the whole MFMA phase hides their latency;
        // the end-of-kt barrier drain is then near-free.
        if (kt + 1 < NKT) {
            #pragma unroll
            for (int ks = 0; ks < 4; ++ks)
                #pragma unroll
                for (int nt = 0; nt < 2; ++nt)
                    bf[cur ^ 1][ks][nt] = gB[(nt * 48 + (kt + 1) * 8 + ks * 2) * 32];
            #pragma unroll
            for (int j = 0; j < 4; ++j)
                async_ld16(gA + (kt + 1) * 4096 + j * 1024,
                           ldsA + (unsigned)((cur ^ 1) * 16384) + j * 1024);
            __builtin_amdgcn_sched_barrier(0);   // pin: prefetch issues before compute
        }
        // ---- compute kt from buf[cur] ----
        const char* Sa = Sr + cur * 16384;
        #pragma unroll
        for (int ks = 0; ks < 4; ++ks) {
            #pragma unroll
            for (int mt = 0; mt < 4; ++mt) {
                v4i af = *(const v4i*)(Sa + mt * 4096 + ks * 1024);
                #pragma unroll
                for (int nt = 0; nt < 2; ++nt)
                    acc[mt][nt] = __builtin_amdgcn_mfma_i32_32x32x32_i8(
                        af, bf[cur][ks][nt], acc[mt][nt], 0, 0, 0);
            }
        }
        // drain (loads issued a full compute phase ago) + make A(kt+1)
        // visible to all waves + all waves done reading buf[cur^1] history.
        __syncthreads();
    }

    // C/D (32x32): col = lane&31 (=fr), row = (reg&3) + 8*(reg>>2) + 4*h
    int* Pc = P + (size_t)NROWS * NPR;   // col-partial region

    // ---- col partials (cheap direction: regs + one shuffle) ----
    #pragma unroll
    for (int nt = 0; nt < 2; ++nt) {
        v16i c = vmax16(vmax16(acc[0][nt], acc[1][nt]),
                        vmax16(acc[2][nt], acc[3][nt]));
        int v = c[0];
        #pragma unroll
        for (int i = 1; i < 16; ++i) v = imax(v, c[i]);
        v = imax(v, __shfl_xor(v, 32, 64));        // combine the two k-halves' rows
        if (h == 0) {
            int col = col0 + wave * 64 + nt * 32 + fr;
            Pc[(size_t)col * NPC + by] = v;            // sole writer
        }
    }

    // ---- row partials via LDS transpose (wave-private scratch in S) ----
    // Safe without extra barrier: regions are wave-private, all waves have
    // passed the final __syncthreads above.
    int* T = (int*)(void*)S + wave * 1152;   // 32 x 36 ints per wave (4608 B)
    const int rrow = lane & 31, seg = lane >> 5;
    #pragma unroll
    for (int mt = 0; mt < 4; ++mt) {
        v16i m = vmax16(acc[mt][0], acc[mt][1]);   // max over this wave's 64 cols
        #pragma unroll
        for (int reg = 0; reg < 16; ++reg) {
            int rl = (reg & 3) + 8 * (reg >> 2) + 4 * h;   // local row 0..31
            T[rl * 36 + fr] = m[reg];
        }
        __builtin_amdgcn_s_waitcnt(0);                     // lgkm drain before transpose read
        const v4i* tr = (const v4i*)(T + rrow * 36 + seg * 16);
        v4i a0 = tr[0], a1 = tr[1], a2 = tr[2], a3 = tr[3];
        v4i m01 = { imax(a0[0],a1[0]), imax(a0[1],a1[1]), imax(a0[2],a1[2]), imax(a0[3],a1[3]) };
        v4i m23 = { imax(a2[0],a3[0]), imax(a2[1],a3[1]), imax(a2[2],a3[2]), imax(a2[3],a3[3]) };
        int v = imax(imax(m01[0], m23[0]), imax(m01[1], m23[1]));
        v = imax(v, imax(imax(m01[2], m23[2]), imax(m01[3], m23[3])));
        v = imax(v, __shfl_xor(v, 32, 64));                // combine the two 16-int segments
        if (seg == 0) {
            int row = row0 + mt * 32 + rrow;
            P[(size_t)row * NPR + bx * 4 + wave] = v;      // sole writer
        }
        __builtin_amdgcn_s_waitcnt(0);                     // reads done before next mt overwrites T
    }
}

// ---- 3: reduce partials -> one max per target (wave per target) ----
// rows (t<8192): 128 partials; cols: 64 partials.
__global__ __launch_bounds__(256) void reduce_kernel(
        const int* __restrict__ P, int* __restrict__ maxes) {
    int t    = blockIdx.x * 4 + (threadIdx.x >> 6);
    int lane = threadIdx.x & 63;
    int v;
    if (t < NROWS) {
        const int* p = P + (size_t)t * NPR;
        v = imax(p[lane], p[lane + 64]);
    } else {
        const int* p = P + (size_t)NROWS * NPR + (size_t)(t - NROWS) * NPC;
        v = p[lane];
    }
    #pragma unroll
    for (int off = 1; off < 64; off <<= 1)
        v = imax(v, __shfl_xor(v, off, 64));
    if (lane == 0) maxes[t] = v;
}

// ---- 4: entropy of Normal log-probs of (1 + max) ----
__global__ __launch_bounds__(256) void finalize_kernel(
        const int* __restrict__ maxes, float* __restrict__ out) {
    int which = blockIdx.x;
    const int* m = maxes + which * NROWS;
    int t = threadIdx.x;
    float s = 0.0f;
    const float dq = 1.0f / (QSCALE * QSCALE);
    for (int i = t; i < NROWS; i += 256) {
        float f = (float)m[i] * dq;
        float z = f * (1.0f / 0.3f);
        float c = -0.5f * z * z + 0.28503427f;
        s += expf(c) * c;
    }
    #pragma unroll
    for (int off = 32; off > 0; off >>= 1) s += __shfl_down(s, off, 64);
    __shared__ float red[4];
    if ((t & 63) == 0) red[t >> 6] = s;
    __syncthreads();
    if (t == 0) out[which] = -(red[0] + red[1] + red[2] + red[3]);
}

extern "C" void kernel_launch(void* const* d_in, const int* in_sizes, int n_in,
                              void* d_out, int out_size, void* d_ws, size_t ws_size,
                              hipStream_t stream) {
    const float* ex = (const float*)d_in[0];
    const float* ey = (const float*)d_in[1];
    float* out = (float*)d_out;

    char* ws = (char*)d_ws;
    char* Xqf   = ws;                                            // 6.29 MB fragment-major
    char* Yqf   = ws + (size_t)NROWS * DDIM;                     // 6.29 MB fragment-major
    int*  P     = (int*)(ws + (size_t)2 * NROWS * DDIM);         // 4 MB rows + 2 MB cols
    int*  maxes = P + (size_t)NROWS * NPR + (size_t)NROWS * NPC; // 64 KB

    hipLaunchKernelGGL(norm_quant_kernel, dim3(2 * NROWS / 4), dim3(256), 0, stream,
                       ex, ey, Xqf, Yqf);
    hipLaunchKernelGGL(gemm_max_kernel, dim3((NROWS / BM) * (NROWS / BN)), dim3(256), 0, stream,
                       Xqf, Yqf, P);
    hipLaunchKernelGGL(reduce_kernel, dim3(NTGT / 4), dim3(256), 0, stream, P, maxes);
    hipLaunchKernelGGL(finalize_kernel, dim3(2), dim3(256), 0, stream, maxes, out);
}